// Round 1
// baseline (275.006 us; speedup 1.0000x reference)
//
#include <hip/hip_runtime.h>

#define CIN   256
#define OC    256
#define K_TOT 2304             // 256*9
#define CCH   32               // channels per K-chunk
#define NCHK  8                // K chunks
#define KCH   288              // k-values per chunk (tap-major: k = tap*32 + c)
#define SSTR  296              // LDS row stride (bf16 elems), 16B-aligned, padded

#define N_DW  (OC * K_TOT)     // deform weight elements (589824)
#define N_OW  (32 * K_TOT)     // padded offset weight elements (73728)
#define N_CVT (2 * N_DW + 2 * N_OW)          // 1327104
#define CVT_BLOCKS (N_CVT / 4 / 256)         // 1296

typedef short  bf16x8 __attribute__((ext_vector_type(8)));
typedef float  f32x4  __attribute__((ext_vector_type(4)));
typedef unsigned short ushort_t;

__device__ __forceinline__ ushort_t f2bf(float f) {
    unsigned u = __builtin_bit_cast(unsigned, f);
    u += 0x7fffu + ((u >> 16) & 1u);          // RNE
    return (ushort_t)(u >> 16);
}
__device__ __forceinline__ float bf2f(short s) {
    return __builtin_bit_cast(float, ((unsigned)(unsigned short)s) << 16);
}

// ---------------------------------------------------------------------------
// prep kernel: (a) weight fp32->bf16 cvt with tap-major K permutation
//   dst[oc][cc][tap][cl] = src[oc][cc*32+cl][tap]   (4 elems/thread)
// (b) input transpose NCHW fp32 -> HWC bf16.
// blockIdx.x < CVT_BLOCKS -> cvt; else transpose (320 blocks).
// ---------------------------------------------------------------------------
__global__ __launch_bounds__(256) void prep_k(
    const float* __restrict__ tdw, const float* __restrict__ sdw,
    const float* __restrict__ tow, const float* __restrict__ sow,
    const float* __restrict__ kin, const float* __restrict__ sin_,
    ushort_t* __restrict__ wk_d, ushort_t* __restrict__ ws_d,
    ushort_t* __restrict__ wk_o, ushort_t* __restrict__ ws_o,
    ushort_t* __restrict__ xt_k, ushort_t* __restrict__ xt_s)
{
    __shared__ ushort_t tile[64][264];    // transpose staging

    if (blockIdx.x < CVT_BLOCKS) {
        const int i = (blockIdx.x * 256 + threadIdx.x) * 4;
        const float* src; ushort_t* dst; int j; bool offw = false;
        if (i < N_DW)                    { src = tdw; dst = wk_d; j = i; }
        else if (i < 2 * N_DW)           { src = sdw; dst = ws_d; j = i - N_DW; }
        else if (i < 2 * N_DW + N_OW)    { src = tow; dst = wk_o; j = i - 2 * N_DW; offw = true; }
        else                             { src = sow; dst = ws_o; j = i - 2 * N_DW - N_OW; offw = true; }
        const int oc = j / K_TOT;
        const int k  = j - oc * K_TOT;
        const int cc = k / KCH;
        const int r  = k - cc * KCH;     // r%4==0, so cl..cl+3 share one tap
        const int tap = r >> 5;
        const int cl  = r & 31;
        ushort4 o4 = {0, 0, 0, 0};
        if (!offw || oc < 18) {
            const float* sp = &src[((size_t)oc * CIN + cc * 32 + cl) * 9 + tap];
            o4.x = f2bf(sp[0]); o4.y = f2bf(sp[9]); o4.z = f2bf(sp[18]); o4.w = f2bf(sp[27]);
        }
        *(ushort4*)&dst[j] = o4;
        return;
    }

    // ---- transpose branch -------------------------------------------------
    const int bx2 = blockIdx.x - CVT_BLOCKS;     // 0..319
    int H, W, b, px0; const float* x; ushort_t* xt;
    if (bx2 < 64) {                       // kernel: 16 b * 4 tiles
        H = 16; W = 16; x = kin; xt = xt_k;
        b = bx2 >> 2; px0 = (bx2 & 3) * 64;
    } else {                              // search: 16 b * 16 tiles
        int t2 = bx2 - 64;
        H = 32; W = 32; x = sin_; xt = xt_s;
        b = t2 >> 4; px0 = (t2 & 15) * 64;
    }
    const int HW = H * W;
    const int t = threadIdx.x, lane = t & 63, wv = t >> 6;
    const float* xb = x + (size_t)b * CIN * HW;

    for (int it = 0; it < 16; ++it) {
        const int ch = wv * 64 + it * 4 + (lane >> 4);
        const int pq = (lane & 15) * 4;
        float4 v = *(const float4*)&xb[(size_t)ch * HW + px0 + pq];
        tile[pq + 0][ch] = f2bf(v.x);
        tile[pq + 1][ch] = f2bf(v.y);
        tile[pq + 2][ch] = f2bf(v.z);
        tile[pq + 3][ch] = f2bf(v.w);
    }
    __syncthreads();
    for (int it = 0; it < 8; ++it) {
        const int px = it * 8 + wv * 2 + (lane >> 5);
        const int cg = (lane & 31) * 8;
        bf16x8 v = *(const bf16x8*)&tile[px][cg];
        *(bf16x8*)&xt[((size_t)b * HW + px0 + px) * 256 + cg] = v;
    }
}

// ---------------------------------------------------------------------------
// Offset conv as bf16 MFMA GEMM from HWC. M=16 px/block, N=32, K=2304.
// 1280 blocks (5/CU). Block = 4 waves: wave = (nt = wv&1, K-half = wv>>1),
// each wave does 4 K-chunks x 9 taps = 36 indep load+MFMA steps; K-halves
// combined through a 2 KB LDS reduce. launch_bounds(256,2) -> 128 VGPRs for
// deep load flight.
// blockIdx.x < 256 -> kernel branch, else search (1024).
// ---------------------------------------------------------------------------
__global__ __launch_bounds__(256, 2) void conv_gemm_k(
    const ushort_t* __restrict__ xt_k, const ushort_t* __restrict__ kwgt,
    const float* __restrict__ kbias, float* __restrict__ kout,
    const ushort_t* __restrict__ xt_s, const ushort_t* __restrict__ swgt,
    const float* __restrict__ sbias, float* __restrict__ sout)
{
    __shared__ float sred[2][64][4];      // [nt][lane][reg]

    int H, W, b, px0;
    const ushort_t* xt; const ushort_t* wgt; const float* bias; float* out;
    if (blockIdx.x < 256) {               // kernel: 16 b * 16 tiles
        H = 16; W = 16; xt = xt_k; wgt = kwgt; bias = kbias; out = kout;
        b = blockIdx.x >> 4; px0 = (blockIdx.x & 15) * 16;
    } else {                              // search: 16 b * 64 tiles
        int t2 = blockIdx.x - 256;
        H = 32; W = 32; xt = xt_s; wgt = swgt; bias = sbias; out = sout;
        b = t2 >> 6; px0 = (t2 & 63) * 16;
    }
    const int HW = H * W;
    const int t = threadIdx.x, lane = t & 63, wv = t >> 6;
    const int l15 = lane & 15;
    const int cg8 = (lane >> 4) * 8;
    const int nt = wv & 1;                // n-tile
    const int kh = wv >> 1;               // K-half

    const int px = px0 + l15;
    const int h  = px / W;
    const int wc = px - h * W;
    const ushort_t* xtb = xt + (size_t)b * HW * 256;

    // per-tap address + validity (lane-varying)
    int  aoff[9];
    bool aok [9];
#pragma unroll
    for (int ks = 0; ks < 9; ++ks) {
        const int y  = h + ks / 3 - 1;
        const int xx = wc + ks % 3 - 1;
        aok [ks] = ((unsigned)y < (unsigned)H) && ((unsigned)xx < (unsigned)W);
        aoff[ks] = aok[ks] ? ((y * W + xx) * 256 + cg8) : 0;
    }
    const ushort_t* wrow = wgt + (size_t)(nt * 16 + l15) * K_TOT + cg8;

    f32x4 acc = {};
    for (int cc = kh * 4; cc < kh * 4 + 4; ++cc) {
#pragma unroll
        for (int ks = 0; ks < 9; ++ks) {
            bf16x8 a = {};
            if (aok[ks]) a = *(const bf16x8*)&xtb[aoff[ks] + cc * 32];
            bf16x8 bb = *(const bf16x8*)&wrow[(size_t)cc * KCH + ks * 32];
            acc = __builtin_amdgcn_mfma_f32_16x16x32_bf16(a, bb, acc, 0, 0, 0);
        }
    }

    if (kh == 1) *(float4*)&sred[nt][lane][0] = *(float4*)&acc;
    __syncthreads();
    if (kh == 0) {
        const float4 o = *(const float4*)&sred[nt][lane][0];
        const int oc = nt * 16 + l15;
        if (oc < 18) {
            const float bs = bias[oc];
            const int prow = (lane >> 4) * 4;
            float4 r = { acc.x + o.x + bs, acc.y + o.y + bs,
                         acc.z + o.z + bs, acc.w + o.w + bs };
            *(float4*)(out + ((size_t)b * 18 + oc) * HW + px0 + prow) = r;
        }
    }
}

// ---------------------------------------------------------------------------
// Deformable conv, bf16 MFMA GEMM from HWC. M=32, N=256, K=2304 tap-major.
// Block = 512 thr = 8 waves; wave = oc column [wv*32,+32), both m-tiles.
//
// Latency-hiding structure (this revision):
//  * bilinear params (corner element-offsets, weights, LDS write offset)
//    held in PERSISTENT registers — no per-chunk sidx/swt LDS round-trip.
//  * corner loads for chunk cc+1 are issued PRE-barrier (after the bX weight
//    group, so FIFO vmcnt lets bX be waited without draining the prefetch).
//  * raw s_barrier with explicit lgkmcnt(0) only — NO vmcnt(0) drain, so the
//    prefetch stays in flight across the barrier and its latency hides under
//    the ~500-cycle MFMA phase (T14 async-STAGE split).
//  * s_setprio(1) around the MFMA phase: resident blocks are at independent
//    phases, so the CU scheduler can favor MFMA-issuing waves (T5).
// Double-buffered smp, ONE barrier/chunk; correctness identical to the
// __syncthreads version: all smp[p] reads are lgkm-drained before any wave
// passes the next barrier, and proc(cc+2)'s writes to smp[p] occur only
// after that barrier.
// grid: 128 kernel-branch + 512 search = 640.
// ---------------------------------------------------------------------------
__device__ __forceinline__ void dcn_load4o(
    bf16x8* c, const ushort_t* __restrict__ xtb, int4 eo, int cb)
{
    c[0] = *(const bf16x8*)&xtb[eo.x + cb];
    c[1] = *(const bf16x8*)&xtb[eo.y + cb];
    c[2] = *(const bf16x8*)&xtb[eo.z + cb];
    c[3] = *(const bf16x8*)&xtb[eo.w + cb];
}
__device__ __forceinline__ void dcn_proc2(
    ushort_t* swb, int so, const bf16x8* c, float4 wt)
{
    bf16x8 r;
#pragma unroll
    for (int j = 0; j < 8; ++j) {
        const float v = wt.x * bf2f(c[0][j]) + wt.y * bf2f(c[1][j])
                      + wt.z * bf2f(c[2][j]) + wt.w * bf2f(c[3][j]);
        r[j] = (short)f2bf(v);
    }
    *(bf16x8*)&swb[so] = r;
}
__device__ __forceinline__ void unit_params(
    int s, const int (*sidx)[9][4], const float (*swt)[9][4],
    int4& eo, float4& wt, int& so)
{
    const int tap = s >> 7;
    const int r   = s & 127;
    const int px  = r >> 2;
    const int cg  = r & 3;
    const int4 id = *(const int4*)sidx[px][tap];
    eo.x = id.x * 256 + cg * 8;
    eo.y = id.y * 256 + cg * 8;
    eo.z = id.z * 256 + cg * 8;
    eo.w = id.w * 256 + cg * 8;
    wt = *(const float4*)swt[px][tap];
    so = px * SSTR + tap * 32 + cg * 8;
}
__device__ __forceinline__ void ldb2(
    bf16x8 (*B)[2], const ushort_t* __restrict__ w0,
    const ushort_t* __restrict__ w1, size_t kg0, int ks0)
{
    B[0][0] = *(const bf16x8*)&w0[kg0 + (size_t)ks0 * 32];
    B[0][1] = *(const bf16x8*)&w1[kg0 + (size_t)ks0 * 32];
    B[1][0] = *(const bf16x8*)&w0[kg0 + (size_t)(ks0 + 1) * 32];
    B[1][1] = *(const bf16x8*)&w1[kg0 + (size_t)(ks0 + 1) * 32];
}
__device__ __forceinline__ void mm2(
    f32x4 (*acc)[2], bf16x8 (*B)[2], ushort_t (*sw)[SSTR],
    int l15, int cg8, int ks0, int n)
{
#pragma unroll
    for (int i = 0; i < n; ++i) {
        bf16x8 a0 = *(const bf16x8*)&sw[l15     ][(ks0 + i) * 32 + cg8];
        bf16x8 a1 = *(const bf16x8*)&sw[16 + l15][(ks0 + i) * 32 + cg8];
        acc[0][0] = __builtin_amdgcn_mfma_f32_16x16x32_bf16(a0, B[i][0], acc[0][0], 0, 0, 0);
        acc[1][0] = __builtin_amdgcn_mfma_f32_16x16x32_bf16(a1, B[i][0], acc[1][0], 0, 0, 0);
        acc[0][1] = __builtin_amdgcn_mfma_f32_16x16x32_bf16(a0, B[i][1], acc[0][1], 0, 0, 0);
        acc[1][1] = __builtin_amdgcn_mfma_f32_16x16x32_bf16(a1, B[i][1], acc[1][1], 0, 0, 0);
    }
}

__global__ __launch_bounds__(512, 4) void deform_gemm_k(
    const ushort_t* __restrict__ xt_k, const float* __restrict__ koffs,
    const ushort_t* __restrict__ kwgt, float* __restrict__ kout,
    const ushort_t* __restrict__ xt_s, const float* __restrict__ soffs,
    const ushort_t* __restrict__ swgt_, float* __restrict__ sout)
{
    __shared__ __align__(16) ushort_t smp[2][32][SSTR];  // 37.9 KB (dbuf)
    __shared__ __align__(16) int      sidx[32][9][4];    // 4.6 KB
    __shared__ __align__(16) float    swt [32][9][4];    // 4.6 KB

    int H, W, b, px0;
    const ushort_t* xt; const float* offs; const ushort_t* wgt; float* out;
    if (blockIdx.x < 128) {               // kernel: 16 b * 8 tiles
        H = 16; W = 16; xt = xt_k; offs = koffs; wgt = kwgt; out = kout;
        b = blockIdx.x >> 3; px0 = (blockIdx.x & 7) * 32;
    } else {                              // search: 16 b * 32 tiles
        int t2 = blockIdx.x - 128;
        H = 32; W = 32; xt = xt_s; offs = soffs; wgt = swgt_; out = sout;
        b = t2 >> 5; px0 = (t2 & 31) * 32;
    }
    const int HW = H * W;
    const int t = threadIdx.x, lane = t & 63, wv = t >> 6;

    // ---- phase 0: bilinear params, one (px,tap) unit per thread -----------
    if (t < 288) {
        const int p = t / 9, k = t - 9 * p;
        const int pix = px0 + p;
        const int h  = pix / W;
        const int wc = pix - h * W;
        const float* ob = offs + (size_t)b * 18 * HW;
        const float dy = ob[(2 * k    ) * HW + pix];
        const float dx = ob[(2 * k + 1) * HW + pix];
        const float sy = (float)(h  + k / 3 - 1) + dy;
        const float sx = (float)(wc + k % 3 - 1) + dx;
        const float y0f = floorf(sy), x0f = floorf(sx);
        const float ly = sy - y0f, lx = sx - x0f;
        const int y0 = (int)y0f, x0 = (int)x0f;
#pragma unroll
        for (int j = 0; j < 4; ++j) {
            const int yy = y0 + (j >> 1);
            const int xx = x0 + (j & 1);
            const bool ok = ((unsigned)yy < (unsigned)H) && ((unsigned)xx < (unsigned)W);
            sidx[p][k][j] = min(max(yy, 0), H - 1) * W + min(max(xx, 0), W - 1);
            const float wj = ((j >> 1) ? ly : 1.f - ly) * ((j & 1) ? lx : 1.f - lx);
            swt[p][k][j] = ok ? wj : 0.f;
        }
    }
    __syncthreads();

    const ushort_t* xtb = xt + (size_t)b * HW * 256;
    const int l15 = lane & 15;
    const int cg8 = (lane >> 4) * 8;
    const int ocb = wv * 32;
    const bool live2 = (t < 128);

    // ---- persistent gather-unit parameters (registers, read once) ---------
    int4 eoff0, eoff1, eoff2 = {};
    float4 uwt0, uwt1, uwt2 = {};
    int swo0, swo1, swo2 = 0;
    unit_params(t,        sidx, swt, eoff0, uwt0, swo0);
    unit_params(t + 512,  sidx, swt, eoff1, uwt1, swo1);
    if (live2) unit_params(t + 1024, sidx, swt, eoff2, uwt2, swo2);

    const ushort_t* wrow0 = wgt + (size_t)(ocb      + l15) * K_TOT + cg8;
    const ushort_t* wrow1 = wgt + (size_t)(ocb + 16 + l15) * K_TOT + cg8;

    f32x4 acc[2][2] = {};
    bf16x8 c0[4], c1[4], c2[4];

    // prefetch chunk 0 corners
    dcn_load4o(c0, xtb, eoff0, 0);
    dcn_load4o(c1, xtb, eoff1, 0);
    if (live2) dcn_load4o(c2, xtb, eoff2, 0);

    for (int cc = 0; cc < NCHK; ++cc) {
        ushort_t (*sw)[SSTR] = smp[cc & 1];
        ushort_t* swb = &sw[0][0];
        const size_t kg0 = (size_t)cc * KCH;

        // ---- combine + LDS write (consumes prefetched c-regs) -------------
        bf16x8 bX[2][2], bY[2][2];
        dcn_proc2(swb, swo0, c0, uwt0);
        // B group 0 (ks 0,1): issued BEFORE the corner prefetch so waiting on
        // it (FIFO vmcnt) does not force the prefetch to retire.
        ldb2(bX, wrow0, wrow1, kg0, 0);
        dcn_proc2(swb, swo1, c1, uwt1);
        if (live2) dcn_proc2(swb, swo2, c2, uwt2);

        // ---- prefetch corners for chunk cc+1 (stays in flight across the
        //      barrier; latency hides under this chunk's MFMA phase) --------
        if (cc < NCHK - 1) {
            const int cb = (cc + 1) * 32;
            dcn_load4o(c0, xtb, eoff0, cb);
            dcn_load4o(c1, xtb, eoff1, cb);
            if (live2) dcn_load4o(c2, xtb, eoff2, cb);
        }

        // ---- raw barrier: drain LDS writes only, NOT the vmem prefetch ----
        asm volatile("s_waitcnt lgkmcnt(0)" ::: "memory");
        __builtin_amdgcn_sched_barrier(0);
        __builtin_amdgcn_s_barrier();
        __builtin_amdgcn_sched_barrier(0);

        // ---- MFMA phase: rolled 2-ks register double-buffer ---------------
        __builtin_amdgcn_s_setprio(1);
        ldb2(bY, wrow0, wrow1, kg0, 2);  mm2(acc, bX, sw, l15, cg8, 0, 2);
        ldb2(bX, wrow0, wrow1, kg0, 4);  mm2(acc, bY, sw, l15, cg8, 2, 2);
        ldb2(bY, wrow0, wrow1, kg0, 6);  mm2(acc, bX, sw, l15, cg8, 4, 2);
        bX[0][0] = *(const bf16x8*)&wrow0[kg0 + 8 * 32];
        bX[0][1] = *(const bf16x8*)&wrow1[kg0 + 8 * 32];
        mm2(acc, bY, sw, l15, cg8, 6, 2);
        mm2(acc, bX, sw, l15, cg8, 8, 1);
        __builtin_amdgcn_s_setprio(0);
    }

    // ---- epilogue ---------------------------------------------------------
    const int prow = (lane >> 4) * 4;
#pragma unroll
    for (int mt = 0; mt < 2; ++mt) {
#pragma unroll
        for (int nt = 0; nt < 2; ++nt) {
            const int oc = ocb + nt * 16 + l15;
            float* op = out + ((size_t)b * OC + oc) * HW + px0 + mt * 16 + prow;
            *(float4*)op = *(float4*)&acc[mt][nt];
        }
    }
}

// ---------------------------------------------------------------------------
// Launcher. Inputs: kernel, search, Toffset_w, Toffset_b, Tdeform_w,
//                   Soffset_w, Soffset_b, Sdeform_w
// Outputs: kernel_out[16,256,16,16], search_out[16,256,32,32],
//          kernel_offset[16,18,16,16], search_offset[16,18,32,32]
// d_ws: 13.2 MB (bf16 weights 2.66 MB + HWC inputs 10.5 MB).
// ---------------------------------------------------------------------------
extern "C" void kernel_launch(void* const* d_in, const int* in_sizes, int n_in,
                              void* d_out, int out_size, void* d_ws, size_t ws_size,
                              hipStream_t stream) {
    const float* kin = (const float*)d_in[0];
    const float* sin_ = (const float*)d_in[1];
    const float* tow = (const float*)d_in[2];
    const float* tob = (const float*)d_in[3];
    const float* tdw = (const float*)d_in[4];
    const float* sow = (const float*)d_in[5];
    const float* sob = (const float*)d_in[6];
    const float* sdw = (const float*)d_in[7];

    float* out = (float*)d_out;
    float* out_k  = out;                                      // 16*256*16*16
    float* out_s  = out_k + (size_t)16 * 256 * 16 * 16;       // 16*256*32*32
    float* out_ko = out_s + (size_t)16 * 256 * 32 * 32;       // 16*18*16*16
    float* out_so = out_ko + (size_t)16 * 18 * 16 * 16;       // 16*18*32*32

    ushort_t* wk_d = (ushort_t*)d_ws;                 // [256][2304] tap-major
    ushort_t* ws_d = wk_d + N_DW;
    ushort_t* wk_o = ws_d + N_DW;                     // [32][2304] tap-major
    ushort_t* ws_o = wk_o + N_OW;
    ushort_t* xt_k = ws_o + N_OW;                     // [16][256][256] HWC bf16
    ushort_t* xt_s = xt_k + (size_t)16 * 256 * 256;   // [16][1024][256]

    prep_k<<<dim3(CVT_BLOCKS + 320), 256, 0, stream>>>(
        tdw, sdw, tow, sow, kin, sin_,
        wk_d, ws_d, wk_o, ws_o, xt_k, xt_s);

    conv_gemm_k<<<dim3(1280), 256, 0, stream>>>(
        xt_k, wk_o, tob, out_ko, xt_s, ws_o, sob, out_so);

    deform_gemm_k<<<dim3(640), 512, 0, stream>>>(
        xt_k, out_ko, wk_d, out_k, xt_s, out_so, ws_d, out_s);
}

// Round 2
// 253.443 us; speedup vs baseline: 1.0851x; 1.0851x over previous
//
#include <hip/hip_runtime.h>

#define CIN   256
#define OC    256
#define K_TOT 2304             // 256*9
#define CCH   32               // channels per K-chunk
#define NCHK  8                // K chunks
#define KCH   288              // k-values per chunk (tap-major: k = tap*32 + c)
#define SSTR  296              // LDS row stride (bf16 elems), 16B-aligned, padded

#define N_DW  (OC * K_TOT)     // deform weight elements (589824)
#define N_OW  (32 * K_TOT)     // padded offset weight elements (73728)
#define N_CVT (2 * N_DW + 2 * N_OW)          // 1327104
#define CVT_BLOCKS (N_CVT / 4 / 256)         // 1296

typedef short  bf16x8 __attribute__((ext_vector_type(8)));
typedef float  f32x4  __attribute__((ext_vector_type(4)));
typedef unsigned short ushort_t;

__device__ __forceinline__ ushort_t f2bf(float f) {
    unsigned u = __builtin_bit_cast(unsigned, f);
    u += 0x7fffu + ((u >> 16) & 1u);          // RNE
    return (ushort_t)(u >> 16);
}
__device__ __forceinline__ float bf2f(short s) {
    return __builtin_bit_cast(float, ((unsigned)(unsigned short)s) << 16);
}

// ---------------------------------------------------------------------------
// prep kernel: (a) weight fp32->bf16 cvt with tap-major K permutation
//   dst[oc][cc][tap][cl] = src[oc][cc*32+cl][tap]   (4 elems/thread)
// (b) input transpose NCHW fp32 -> HWC bf16.
// blockIdx.x < CVT_BLOCKS -> cvt; else transpose (320 blocks).
// ---------------------------------------------------------------------------
__global__ __launch_bounds__(256) void prep_k(
    const float* __restrict__ tdw, const float* __restrict__ sdw,
    const float* __restrict__ tow, const float* __restrict__ sow,
    const float* __restrict__ kin, const float* __restrict__ sin_,
    ushort_t* __restrict__ wk_d, ushort_t* __restrict__ ws_d,
    ushort_t* __restrict__ wk_o, ushort_t* __restrict__ ws_o,
    ushort_t* __restrict__ xt_k, ushort_t* __restrict__ xt_s)
{
    __shared__ ushort_t tile[64][264];    // transpose staging

    if (blockIdx.x < CVT_BLOCKS) {
        const int i = (blockIdx.x * 256 + threadIdx.x) * 4;
        const float* src; ushort_t* dst; int j; bool offw = false;
        if (i < N_DW)                    { src = tdw; dst = wk_d; j = i; }
        else if (i < 2 * N_DW)           { src = sdw; dst = ws_d; j = i - N_DW; }
        else if (i < 2 * N_DW + N_OW)    { src = tow; dst = wk_o; j = i - 2 * N_DW; offw = true; }
        else                             { src = sow; dst = ws_o; j = i - 2 * N_DW - N_OW; offw = true; }
        const int oc = j / K_TOT;
        const int k  = j - oc * K_TOT;
        const int cc = k / KCH;
        const int r  = k - cc * KCH;     // r%4==0, so cl..cl+3 share one tap
        const int tap = r >> 5;
        const int cl  = r & 31;
        ushort4 o4 = {0, 0, 0, 0};
        if (!offw || oc < 18) {
            const float* sp = &src[((size_t)oc * CIN + cc * 32 + cl) * 9 + tap];
            o4.x = f2bf(sp[0]); o4.y = f2bf(sp[9]); o4.z = f2bf(sp[18]); o4.w = f2bf(sp[27]);
        }
        *(ushort4*)&dst[j] = o4;
        return;
    }

    // ---- transpose branch -------------------------------------------------
    const int bx2 = blockIdx.x - CVT_BLOCKS;     // 0..319
    int H, W, b, px0; const float* x; ushort_t* xt;
    if (bx2 < 64) {                       // kernel: 16 b * 4 tiles
        H = 16; W = 16; x = kin; xt = xt_k;
        b = bx2 >> 2; px0 = (bx2 & 3) * 64;
    } else {                              // search: 16 b * 16 tiles
        int t2 = bx2 - 64;
        H = 32; W = 32; x = sin_; xt = xt_s;
        b = t2 >> 4; px0 = (t2 & 15) * 64;
    }
    const int HW = H * W;
    const int t = threadIdx.x, lane = t & 63, wv = t >> 6;
    const float* xb = x + (size_t)b * CIN * HW;

    for (int it = 0; it < 16; ++it) {
        const int ch = wv * 64 + it * 4 + (lane >> 4);
        const int pq = (lane & 15) * 4;
        float4 v = *(const float4*)&xb[(size_t)ch * HW + px0 + pq];
        tile[pq + 0][ch] = f2bf(v.x);
        tile[pq + 1][ch] = f2bf(v.y);
        tile[pq + 2][ch] = f2bf(v.z);
        tile[pq + 3][ch] = f2bf(v.w);
    }
    __syncthreads();
    for (int it = 0; it < 8; ++it) {
        const int px = it * 8 + wv * 2 + (lane >> 5);
        const int cg = (lane & 31) * 8;
        bf16x8 v = *(const bf16x8*)&tile[px][cg];
        *(bf16x8*)&xt[((size_t)b * HW + px0 + px) * 256 + cg] = v;
    }
}

// ---------------------------------------------------------------------------
// Offset conv as bf16 MFMA GEMM from HWC. M=16 px/block, N=32, K=2304.
// 1280 blocks (5/CU). Block = 4 waves: wave = (nt = wv&1, K-half = wv>>1),
// each wave does 4 K-chunks x 9 taps = 36 indep load+MFMA steps; K-halves
// combined through a 2 KB LDS reduce. launch_bounds(256,2) -> 128 VGPRs for
// deep load flight.
// blockIdx.x < 256 -> kernel branch, else search (1024).
// ---------------------------------------------------------------------------
__global__ __launch_bounds__(256, 2) void conv_gemm_k(
    const ushort_t* __restrict__ xt_k, const ushort_t* __restrict__ kwgt,
    const float* __restrict__ kbias, float* __restrict__ kout,
    const ushort_t* __restrict__ xt_s, const ushort_t* __restrict__ swgt,
    const float* __restrict__ sbias, float* __restrict__ sout)
{
    __shared__ float sred[2][64][4];      // [nt][lane][reg]

    int H, W, b, px0;
    const ushort_t* xt; const ushort_t* wgt; const float* bias; float* out;
    if (blockIdx.x < 256) {               // kernel: 16 b * 16 tiles
        H = 16; W = 16; xt = xt_k; wgt = kwgt; bias = kbias; out = kout;
        b = blockIdx.x >> 4; px0 = (blockIdx.x & 15) * 16;
    } else {                              // search: 16 b * 64 tiles
        int t2 = blockIdx.x - 256;
        H = 32; W = 32; xt = xt_s; wgt = swgt; bias = sbias; out = sout;
        b = t2 >> 6; px0 = (t2 & 63) * 16;
    }
    const int HW = H * W;
    const int t = threadIdx.x, lane = t & 63, wv = t >> 6;
    const int l15 = lane & 15;
    const int cg8 = (lane >> 4) * 8;
    const int nt = wv & 1;                // n-tile
    const int kh = wv >> 1;               // K-half

    const int px = px0 + l15;
    const int h  = px / W;
    const int wc = px - h * W;
    const ushort_t* xtb = xt + (size_t)b * HW * 256;

    // per-tap address + validity (lane-varying)
    int  aoff[9];
    bool aok [9];
#pragma unroll
    for (int ks = 0; ks < 9; ++ks) {
        const int y  = h + ks / 3 - 1;
        const int xx = wc + ks % 3 - 1;
        aok [ks] = ((unsigned)y < (unsigned)H) && ((unsigned)xx < (unsigned)W);
        aoff[ks] = aok[ks] ? ((y * W + xx) * 256 + cg8) : 0;
    }
    const ushort_t* wrow = wgt + (size_t)(nt * 16 + l15) * K_TOT + cg8;

    f32x4 acc = {};
    for (int cc = kh * 4; cc < kh * 4 + 4; ++cc) {
#pragma unroll
        for (int ks = 0; ks < 9; ++ks) {
            bf16x8 a = {};
            if (aok[ks]) a = *(const bf16x8*)&xtb[aoff[ks] + cc * 32];
            bf16x8 bb = *(const bf16x8*)&wrow[(size_t)cc * KCH + ks * 32];
            acc = __builtin_amdgcn_mfma_f32_16x16x32_bf16(a, bb, acc, 0, 0, 0);
        }
    }

    if (kh == 1) *(float4*)&sred[nt][lane][0] = *(float4*)&acc;
    __syncthreads();
    if (kh == 0) {
        const float4 o = *(const float4*)&sred[nt][lane][0];
        const int oc = nt * 16 + l15;
        if (oc < 18) {
            const float bs = bias[oc];
            const int prow = (lane >> 4) * 4;
            float4 r = { acc.x + o.x + bs, acc.y + o.y + bs,
                         acc.z + o.z + bs, acc.w + o.w + bs };
            *(float4*)(out + ((size_t)b * 18 + oc) * HW + px0 + prow) = r;
        }
    }
}

// ---------------------------------------------------------------------------
// Deformable conv, bf16 MFMA GEMM from HWC. M=32, N=256, K=2304 tap-major.
// Block = 512 thr = 8 waves; wave = oc column [wv*32,+32), both m-tiles.
//
// Round-2 structure (spill-safe latency hiding):
//  * unit 0 ONLY is prefetched: its bilinear params live in persistent
//    registers (9 VGPRs) and its 4 corner loads for chunk cc+1 are issued
//    pre-barrier, staying in flight across the barrier (16 VGPRs).
//    Units 1/2 keep the baseline pattern (per-chunk LDS param read, loads
//    consumed in-phase) to cap register pressure — round 1 proved that
//    prefetching all 3 units spills (WRITE_SIZE 20->56 MB scratch traffic).
//  * raw s_barrier with lgkmcnt(0) only — no vmcnt(0) drain, so the unit-0
//    prefetch and the pre-issued bX weight loads cross the barrier and their
//    latency hides under the MFMA phase (T14).
//  * s_setprio(1) around the MFMA phase (T5).
//  * launch_bounds(512, 2): VGPR cap 256 (was 128) — round 1 spilled BELOW
//    the 128 cap, so give the allocator headroom; LDS (47 KB) still permits
//    3 blocks/CU.
// Double-buffered smp, ONE barrier/chunk (same safety argument as baseline:
// each wave's lgkmcnt(0) before the barrier drains its own smp reads, and
// buffer p is only overwritten two barriers later).
// grid: 128 kernel-branch + 512 search = 640.
// ---------------------------------------------------------------------------
__device__ __forceinline__ void dcn_load4(
    bf16x8* c, const ushort_t* __restrict__ xtb, int4 id, int cb)
{
    c[0] = *(const bf16x8*)&xtb[(size_t)id.x * 256 + cb];
    c[1] = *(const bf16x8*)&xtb[(size_t)id.y * 256 + cb];
    c[2] = *(const bf16x8*)&xtb[(size_t)id.z * 256 + cb];
    c[3] = *(const bf16x8*)&xtb[(size_t)id.w * 256 + cb];
}
__device__ __forceinline__ void dcn_load4o(
    bf16x8* c, const ushort_t* __restrict__ xtb, int4 eo, int cb)
{
    c[0] = *(const bf16x8*)&xtb[eo.x + cb];
    c[1] = *(const bf16x8*)&xtb[eo.y + cb];
    c[2] = *(const bf16x8*)&xtb[eo.z + cb];
    c[3] = *(const bf16x8*)&xtb[eo.w + cb];
}
__device__ __forceinline__ void dcn_proc(
    ushort_t (*sw)[SSTR], int px, int tap, int cg, const bf16x8* c, float4 wt)
{
    bf16x8 r;
#pragma unroll
    for (int j = 0; j < 8; ++j) {
        const float v = wt.x * bf2f(c[0][j]) + wt.y * bf2f(c[1][j])
                      + wt.z * bf2f(c[2][j]) + wt.w * bf2f(c[3][j]);
        r[j] = (short)f2bf(v);
    }
    *(bf16x8*)&sw[px][tap * 32 + cg * 8] = r;
}
__device__ __forceinline__ void dcn_proc2(
    ushort_t* swb, int so, const bf16x8* c, float4 wt)
{
    bf16x8 r;
#pragma unroll
    for (int j = 0; j < 8; ++j) {
        const float v = wt.x * bf2f(c[0][j]) + wt.y * bf2f(c[1][j])
                      + wt.z * bf2f(c[2][j]) + wt.w * bf2f(c[3][j]);
        r[j] = (short)f2bf(v);
    }
    *(bf16x8*)&swb[so] = r;
}
__device__ __forceinline__ void ldb2(
    bf16x8 (*B)[2], const ushort_t* __restrict__ w0,
    const ushort_t* __restrict__ w1, size_t kg0, int ks0)
{
    B[0][0] = *(const bf16x8*)&w0[kg0 + (size_t)ks0 * 32];
    B[0][1] = *(const bf16x8*)&w1[kg0 + (size_t)ks0 * 32];
    B[1][0] = *(const bf16x8*)&w0[kg0 + (size_t)(ks0 + 1) * 32];
    B[1][1] = *(const bf16x8*)&w1[kg0 + (size_t)(ks0 + 1) * 32];
}
__device__ __forceinline__ void mm2(
    f32x4 (*acc)[2], bf16x8 (*B)[2], ushort_t (*sw)[SSTR],
    int l15, int cg8, int ks0, int n)
{
#pragma unroll
    for (int i = 0; i < n; ++i) {
        bf16x8 a0 = *(const bf16x8*)&sw[l15     ][(ks0 + i) * 32 + cg8];
        bf16x8 a1 = *(const bf16x8*)&sw[16 + l15][(ks0 + i) * 32 + cg8];
        acc[0][0] = __builtin_amdgcn_mfma_f32_16x16x32_bf16(a0, B[i][0], acc[0][0], 0, 0, 0);
        acc[1][0] = __builtin_amdgcn_mfma_f32_16x16x32_bf16(a1, B[i][0], acc[1][0], 0, 0, 0);
        acc[0][1] = __builtin_amdgcn_mfma_f32_16x16x32_bf16(a0, B[i][1], acc[0][1], 0, 0, 0);
        acc[1][1] = __builtin_amdgcn_mfma_f32_16x16x32_bf16(a1, B[i][1], acc[1][1], 0, 0, 0);
    }
}

__global__ __launch_bounds__(512, 2) void deform_gemm_k(
    const ushort_t* __restrict__ xt_k, const float* __restrict__ koffs,
    const ushort_t* __restrict__ kwgt, float* __restrict__ kout,
    const ushort_t* __restrict__ xt_s, const float* __restrict__ soffs,
    const ushort_t* __restrict__ swgt_, float* __restrict__ sout)
{
    __shared__ __align__(16) ushort_t smp[2][32][SSTR];  // 37.9 KB (dbuf)
    __shared__ __align__(16) int      sidx[32][9][4];    // 4.6 KB
    __shared__ __align__(16) float    swt [32][9][4];    // 4.6 KB

    int H, W, b, px0;
    const ushort_t* xt; const float* offs; const ushort_t* wgt; float* out;
    if (blockIdx.x < 128) {               // kernel: 16 b * 8 tiles
        H = 16; W = 16; xt = xt_k; offs = koffs; wgt = kwgt; out = kout;
        b = blockIdx.x >> 3; px0 = (blockIdx.x & 7) * 32;
    } else {                              // search: 16 b * 32 tiles
        int t2 = blockIdx.x - 128;
        H = 32; W = 32; xt = xt_s; offs = soffs; wgt = swgt_; out = sout;
        b = t2 >> 5; px0 = (t2 & 31) * 32;
    }
    const int HW = H * W;
    const int t = threadIdx.x, lane = t & 63, wv = t >> 6;

    // ---- phase 0: bilinear params, one (px,tap) unit per thread -----------
    if (t < 288) {
        const int p = t / 9, k = t - 9 * p;
        const int pix = px0 + p;
        const int h  = pix / W;
        const int wc = pix - h * W;
        const float* ob = offs + (size_t)b * 18 * HW;
        const float dy = ob[(2 * k    ) * HW + pix];
        const float dx = ob[(2 * k + 1) * HW + pix];
        const float sy = (float)(h  + k / 3 - 1) + dy;
        const float sx = (float)(wc + k % 3 - 1) + dx;
        const float y0f = floorf(sy), x0f = floorf(sx);
        const float ly = sy - y0f, lx = sx - x0f;
        const int y0 = (int)y0f, x0 = (int)x0f;
#pragma unroll
        for (int j = 0; j < 4; ++j) {
            const int yy = y0 + (j >> 1);
            const int xx = x0 + (j & 1);
            const bool ok = ((unsigned)yy < (unsigned)H) && ((unsigned)xx < (unsigned)W);
            sidx[p][k][j] = min(max(yy, 0), H - 1) * W + min(max(xx, 0), W - 1);
            const float wj = ((j >> 1) ? ly : 1.f - ly) * ((j & 1) ? lx : 1.f - lx);
            swt[p][k][j] = ok ? wj : 0.f;
        }
    }
    __syncthreads();

    const ushort_t* xtb = xt + (size_t)b * HW * 256;
    const int l15 = lane & 15;
    const int cg8 = (lane >> 4) * 8;
    const int ocb = wv * 32;
    const bool live2 = (t < 128);

    // ---- unit 0: persistent params (prefetched unit) ----------------------
    int4 eoff0; float4 uwt0; int swo0;
    {
        const int tap = t >> 7;
        const int r   = t & 127;
        const int px  = r >> 2;
        const int cg  = r & 3;
        const int4 id = *(const int4*)sidx[px][tap];
        eoff0.x = id.x * 256 + cg * 8;
        eoff0.y = id.y * 256 + cg * 8;
        eoff0.z = id.z * 256 + cg * 8;
        eoff0.w = id.w * 256 + cg * 8;
        uwt0 = *(const float4*)swt[px][tap];
        swo0 = px * SSTR + tap * 32 + cg * 8;
    }
    // ---- units 1,2: geometry only, params re-read from LDS each chunk -----
    int upx1, utap1, ucg1;
    { const int s = t + 512;  utap1 = s >> 7; const int r = s & 127; upx1 = r >> 2; ucg1 = r & 3; }
    int upx2 = 0, utap2 = 0, ucg2 = 0;
    if (live2) { const int s = t + 1024; utap2 = s >> 7; const int r = s & 127; upx2 = r >> 2; ucg2 = r & 3; }

    const ushort_t* wrow0 = wgt + (size_t)(ocb      + l15) * K_TOT + cg8;
    const ushort_t* wrow1 = wgt + (size_t)(ocb + 16 + l15) * K_TOT + cg8;

    f32x4 acc[2][2] = {};
    bf16x8 c0[4];

    // prefetch chunk 0, unit 0
    dcn_load4o(c0, xtb, eoff0, 0);

    for (int cc = 0; cc < NCHK; ++cc) {
        ushort_t (*sw)[SSTR] = smp[cc & 1];
        ushort_t* swb = &sw[0][0];
        const int cb = cc * 32;
        const size_t kg0 = (size_t)cc * KCH;

        // ---- gather: units 1,2 loads (in-phase), bX weights ---------------
        bf16x8 c1[4], c2[4];
        const int4   id1 = *(const int4*)  sidx[upx1][utap1];
        const float4 wt1 = *(const float4*)swt [upx1][utap1];
        dcn_load4(c1, xtb, id1, cb + ucg1 * 8);
        int4 id2 = {}; float4 wt2 = {};
        if (live2) {
            id2 = *(const int4*)  sidx[upx2][utap2];
            wt2 = *(const float4*)swt [upx2][utap2];
            dcn_load4(c2, xtb, id2, cb + ucg2 * 8);
        }
        bf16x8 bX[2][2], bY[2][2];
        ldb2(bX, wrow0, wrow1, kg0, 0);

        // unit 0: consume prefetched corners, then issue next chunk's loads
        dcn_proc2(swb, swo0, c0, uwt0);
        if (cc < NCHK - 1) dcn_load4o(c0, xtb, eoff0, cb + 32);

        dcn_proc(sw, upx1, utap1, ucg1, c1, wt1);
        if (live2) dcn_proc(sw, upx2, utap2, ucg2, c2, wt2);

        // ---- raw barrier: drain LDS ops only, vmem stays in flight --------
        asm volatile("s_waitcnt lgkmcnt(0)" ::: "memory");
        __builtin_amdgcn_sched_barrier(0);
        __builtin_amdgcn_s_barrier();
        __builtin_amdgcn_sched_barrier(0);

        // ---- MFMA phase: rolled 2-ks register double-buffer ---------------
        __builtin_amdgcn_s_setprio(1);
        ldb2(bY, wrow0, wrow1, kg0, 2);  mm2(acc, bX, sw, l15, cg8, 0, 2);
        ldb2(bX, wrow0, wrow1, kg0, 4);  mm2(acc, bY, sw, l15, cg8, 2, 2);
        ldb2(bY, wrow0, wrow1, kg0, 6);  mm2(acc, bX, sw, l15, cg8, 4, 2);
        bX[0][0] = *(const bf16x8*)&wrow0[kg0 + 8 * 32];
        bX[0][1] = *(const bf16x8*)&wrow1[kg0 + 8 * 32];
        mm2(acc, bY, sw, l15, cg8, 6, 2);
        mm2(acc, bX, sw, l15, cg8, 8, 1);
        __builtin_amdgcn_s_setprio(0);
    }

    // ---- epilogue ---------------------------------------------------------
    const int prow = (lane >> 4) * 4;
#pragma unroll
    for (int mt = 0; mt < 2; ++mt) {
#pragma unroll
        for (int nt = 0; nt < 2; ++nt) {
            const int oc = ocb + nt * 16 + l15;
            float* op = out + ((size_t)b * OC + oc) * HW + px0 + mt * 16 + prow;
            *(float4*)op = *(float4*)&acc[mt][nt];
        }
    }
}

// ---------------------------------------------------------------------------
// Launcher. Inputs: kernel, search, Toffset_w, Toffset_b, Tdeform_w,
//                   Soffset_w, Soffset_b, Sdeform_w
// Outputs: kernel_out[16,256,16,16], search_out[16,256,32,32],
//          kernel_offset[16,18,16,16], search_offset[16,18,32,32]
// d_ws: 13.2 MB (bf16 weights 2.66 MB + HWC inputs 10.5 MB).
// ---------------------------------------------------------------------------
extern "C" void kernel_launch(void* const* d_in, const int* in_sizes, int n_in,
                              void* d_out, int out_size, void* d_ws, size_t ws_size,
                              hipStream_t stream) {
    const float* kin = (const float*)d_in[0];
    const float* sin_ = (const float*)d_in[1];
    const float* tow = (const float*)d_in[2];
    const float* tob = (const float*)d_in[3];
    const float* tdw = (const float*)d_in[4];
    const float* sow = (const float*)d_in[5];
    const float* sob = (const float*)d_in[6];
    const float* sdw = (const float*)d_in[7];

    float* out = (float*)d_out;
    float* out_k  = out;                                      // 16*256*16*16
    float* out_s  = out_k + (size_t)16 * 256 * 16 * 16;       // 16*256*32*32
    float* out_ko = out_s + (size_t)16 * 256 * 32 * 32;       // 16*18*16*16
    float* out_so = out_ko + (size_t)16 * 18 * 16 * 16;       // 16*18*32*32

    ushort_t* wk_d = (ushort_t*)d_ws;                 // [256][2304] tap-major
    ushort_t* ws_d = wk_d + N_DW;
    ushort_t* wk_o = ws_d + N_DW;                     // [32][2304] tap-major
    ushort_t* ws_o = wk_o + N_OW;
    ushort_t* xt_k = ws_o + N_OW;                     // [16][256][256] HWC bf16
    ushort_t* xt_s = xt_k + (size_t)16 * 256 * 256;   // [16][1024][256]

    prep_k<<<dim3(CVT_BLOCKS + 320), 256, 0, stream>>>(
        tdw, sdw, tow, sow, kin, sin_,
        wk_d, ws_d, wk_o, ws_o, xt_k, xt_s);

    conv_gemm_k<<<dim3(1280), 256, 0, stream>>>(
        xt_k, wk_o, tob, out_ko, xt_s, ws_o, sob, out_so);

    deform_gemm_k<<<dim3(640), 512, 0, stream>>>(
        xt_k, out_ko, wk_d, out_k, xt_s, out_so, ws_d, out_s);
}

// Round 3
// 207.677 us; speedup vs baseline: 1.3242x; 1.2204x over previous
//
#include <hip/hip_runtime.h>

#define CIN   256
#define OC    256
#define K_TOT 2304             // 256*9
#define CCH   32               // channels per K-chunk
#define NCHK  8                // K chunks
#define KCH   288              // k-values per chunk (tap-major: k = tap*32 + c)
#define SSTR  296              // LDS row stride (bf16 elems), 16B-aligned, padded
#define DM    64               // px per block (deform + conv), M-tile
#define DUNITS (DM * 9 * 4)    // 2304 gather units per chunk

#define N_DW  (OC * K_TOT)     // deform weight elements (589824)
#define N_OW  (32 * K_TOT)     // padded offset weight elements (73728)
#define N_CVT (2 * N_DW + 2 * N_OW)          // 1327104
#define CVT_BLOCKS (N_CVT / 4 / 256)         // 1296

typedef short  bf16x8 __attribute__((ext_vector_type(8)));
typedef float  f32x4  __attribute__((ext_vector_type(4)));
typedef unsigned short ushort_t;

__device__ __forceinline__ ushort_t f2bf(float f) {
    unsigned u = __builtin_bit_cast(unsigned, f);
    u += 0x7fffu + ((u >> 16) & 1u);          // RNE
    return (ushort_t)(u >> 16);
}
__device__ __forceinline__ float bf2f(short s) {
    return __builtin_bit_cast(float, ((unsigned)(unsigned short)s) << 16);
}

// ---------------------------------------------------------------------------
// prep kernel: (a) weight fp32->bf16 cvt with tap-major K permutation
//   dst[oc][cc][tap][cl] = src[oc][cc*32+cl][tap]   (4 elems/thread)
// (b) input transpose NCHW fp32 -> HWC bf16.
// blockIdx.x < CVT_BLOCKS -> cvt; else transpose (320 blocks).
// ---------------------------------------------------------------------------
__global__ __launch_bounds__(256) void prep_k(
    const float* __restrict__ tdw, const float* __restrict__ sdw,
    const float* __restrict__ tow, const float* __restrict__ sow,
    const float* __restrict__ kin, const float* __restrict__ sin_,
    ushort_t* __restrict__ wk_d, ushort_t* __restrict__ ws_d,
    ushort_t* __restrict__ wk_o, ushort_t* __restrict__ ws_o,
    ushort_t* __restrict__ xt_k, ushort_t* __restrict__ xt_s)
{
    __shared__ ushort_t tile[64][264];    // transpose staging

    if (blockIdx.x < CVT_BLOCKS) {
        const int i = (blockIdx.x * 256 + threadIdx.x) * 4;
        const float* src; ushort_t* dst; int j; bool offw = false;
        if (i < N_DW)                    { src = tdw; dst = wk_d; j = i; }
        else if (i < 2 * N_DW)           { src = sdw; dst = ws_d; j = i - N_DW; }
        else if (i < 2 * N_DW + N_OW)    { src = tow; dst = wk_o; j = i - 2 * N_DW; offw = true; }
        else                             { src = sow; dst = ws_o; j = i - 2 * N_DW - N_OW; offw = true; }
        const int oc = j / K_TOT;
        const int k  = j - oc * K_TOT;
        const int cc = k / KCH;
        const int r  = k - cc * KCH;     // r%4==0, so cl..cl+3 share one tap
        const int tap = r >> 5;
        const int cl  = r & 31;
        ushort4 o4 = {0, 0, 0, 0};
        if (!offw || oc < 18) {
            const float* sp = &src[((size_t)oc * CIN + cc * 32 + cl) * 9 + tap];
            o4.x = f2bf(sp[0]); o4.y = f2bf(sp[9]); o4.z = f2bf(sp[18]); o4.w = f2bf(sp[27]);
        }
        *(ushort4*)&dst[j] = o4;
        return;
    }

    // ---- transpose branch -------------------------------------------------
    const int bx2 = blockIdx.x - CVT_BLOCKS;     // 0..319
    int H, W, b, px0; const float* x; ushort_t* xt;
    if (bx2 < 64) {                       // kernel: 16 b * 4 tiles
        H = 16; W = 16; x = kin; xt = xt_k;
        b = bx2 >> 2; px0 = (bx2 & 3) * 64;
    } else {                              // search: 16 b * 16 tiles
        int t2 = bx2 - 64;
        H = 32; W = 32; x = sin_; xt = xt_s;
        b = t2 >> 4; px0 = (t2 & 15) * 64;
    }
    const int HW = H * W;
    const int t = threadIdx.x, lane = t & 63, wv = t >> 6;
    const float* xb = x + (size_t)b * CIN * HW;

    for (int it = 0; it < 16; ++it) {
        const int ch = wv * 64 + it * 4 + (lane >> 4);
        const int pq = (lane & 15) * 4;
        float4 v = *(const float4*)&xb[(size_t)ch * HW + px0 + pq];
        tile[pq + 0][ch] = f2bf(v.x);
        tile[pq + 1][ch] = f2bf(v.y);
        tile[pq + 2][ch] = f2bf(v.z);
        tile[pq + 3][ch] = f2bf(v.w);
    }
    __syncthreads();
    for (int it = 0; it < 8; ++it) {
        const int px = it * 8 + wv * 2 + (lane >> 5);
        const int cg = (lane & 31) * 8;
        bf16x8 v = *(const bf16x8*)&tile[px][cg];
        *(bf16x8*)&xt[((size_t)b * HW + px0 + px) * 256 + cg] = v;
    }
}

// ---------------------------------------------------------------------------
// Offset conv as bf16 MFMA GEMM from HWC. M=64 px/block, N=32, K=2304.
// 320 blocks, 256 thr = 4 waves; wave = K-quarter (2 chunks). Inside each
// wave: nt(2) x mt(4) loops so A and B are each read from global EXACTLY ONCE
// per block: traffic 283 MB (M=16 version) -> 141 MB. K-quarters combined
// through a 24.6 KB LDS reduce.
// blockIdx.x < 64 -> kernel branch, else search (256).
// ---------------------------------------------------------------------------
__global__ __launch_bounds__(256, 2) void conv_gemm_k(
    const ushort_t* __restrict__ xt_k, const ushort_t* __restrict__ kwgt,
    const float* __restrict__ kbias, float* __restrict__ kout,
    const ushort_t* __restrict__ xt_s, const ushort_t* __restrict__ swgt,
    const float* __restrict__ sbias, float* __restrict__ sout)
{
    __shared__ float sred[3][4][2][64][4];   // [kh-1][mt][nt][lane][reg]

    int H, W, sh, b, px0;
    const ushort_t* xt; const ushort_t* wgt; const float* bias; float* out;
    if (blockIdx.x < 64) {                // kernel: 16 b * 4 tiles
        H = 16; W = 16; sh = 4; xt = xt_k; wgt = kwgt; bias = kbias; out = kout;
        b = blockIdx.x >> 2; px0 = (blockIdx.x & 3) * 64;
    } else {                              // search: 16 b * 16 tiles
        int t2 = blockIdx.x - 64;
        H = 32; W = 32; sh = 5; xt = xt_s; wgt = swgt; bias = sbias; out = sout;
        b = t2 >> 4; px0 = (t2 & 15) * 64;
    }
    const int HW = H * W;
    const int t = threadIdx.x, lane = t & 63, kh = t >> 6;
    const int l15 = lane & 15;
    const int cg8 = (lane >> 4) * 8;
    const ushort_t* xtb = xt + (size_t)b * HW * 256;

    // per-mt pixel coords (lane-varying)
    int h[4], wc[4];
#pragma unroll
    for (int mt = 0; mt < 4; ++mt) {
        const int px = px0 + mt * 16 + l15;
        h[mt]  = px >> sh;
        wc[mt] = px & (W - 1);
    }
    const ushort_t* wrow0 = wgt + (size_t)(l15)      * K_TOT + cg8;
    const ushort_t* wrow1 = wgt + (size_t)(16 + l15) * K_TOT + cg8;

    f32x4 acc[4][2] = {};
    for (int cc = kh * 2; cc < kh * 2 + 2; ++cc) {
        const int cb = cc * 32 + cg8;
#pragma unroll
        for (int ks = 0; ks < 9; ++ks) {
            const bf16x8 b0 = *(const bf16x8*)&wrow0[(size_t)cc * KCH + ks * 32];
            const bf16x8 b1 = *(const bf16x8*)&wrow1[(size_t)cc * KCH + ks * 32];
            const int dy = ks / 3 - 1, dx = ks % 3 - 1;
#pragma unroll
            for (int mt = 0; mt < 4; ++mt) {
                const int y  = h[mt] + dy;
                const int xx = wc[mt] + dx;
                const bool ok = ((unsigned)y < (unsigned)H) && ((unsigned)xx < (unsigned)W);
                bf16x8 a = {};
                if (ok) a = *(const bf16x8*)&xtb[(size_t)(((y << sh) + xx) * 256 + cb)];
                acc[mt][0] = __builtin_amdgcn_mfma_f32_16x16x32_bf16(a, b0, acc[mt][0], 0, 0, 0);
                acc[mt][1] = __builtin_amdgcn_mfma_f32_16x16x32_bf16(a, b1, acc[mt][1], 0, 0, 0);
            }
        }
    }

    if (kh > 0) {
#pragma unroll
        for (int mt = 0; mt < 4; ++mt)
#pragma unroll
            for (int nt = 0; nt < 2; ++nt)
                *(float4*)&sred[kh - 1][mt][nt][lane][0] = *(float4*)&acc[mt][nt];
    }
    __syncthreads();
    if (kh == 0) {
        const int prow = (lane >> 4) * 4;
#pragma unroll
        for (int nt = 0; nt < 2; ++nt) {
            const int oc = nt * 16 + l15;
            if (oc < 18) {
                const float bs = bias[oc];
#pragma unroll
                for (int mt = 0; mt < 4; ++mt) {
                    float4 r = *(float4*)&acc[mt][nt];
#pragma unroll
                    for (int q = 0; q < 3; ++q) {
                        const float4 o = *(const float4*)&sred[q][mt][nt][lane][0];
                        r.x += o.x; r.y += o.y; r.z += o.z; r.w += o.w;
                    }
                    r.x += bs; r.y += bs; r.z += bs; r.w += bs;
                    *(float4*)(out + ((size_t)b * 18 + oc) * HW + px0 + mt * 16 + prow) = r;
                }
            }
        }
    }
}

// ---------------------------------------------------------------------------
// Deformable conv, bf16 MFMA GEMM from HWC. M=64, N=256, K=2304 tap-major.
// 320 blocks x 512 thr (8 waves); wave = oc column [wv*32,+32), mt-loop x4.
//
// Round-3 structure: traffic-minimizing M=64 tile. Per-block weight read is
// 1.18 MB regardless of M, so M=64 halves total weight traffic vs M=32
// (755 -> 377 MB); gather traffic is M-invariant. Theory: deform is bound by
// L2 line-request throughput (~10 TB/s effective observed across rounds 0-2,
// insensitive to occupancy), so time ~ traffic.
//  * smp single-buffered [64][SSTR] (37.9 KB) + params (18.4 KB) = 56.3 KB
//    -> 2 blocks/CU. Two raw lgkm-only barriers per chunk (write->read,
//    read->next-write); vmem stays in flight across both.
//  * launch_bounds(512,4) caps VGPR at 128 => 16 waves/CU => both blocks
//    resident. Gather params re-read from LDS per chunk (register-safe,
//    round-1 spill lesson). acc[4][2] = 32 VGPR.
//  * s_setprio(1) around MFMA phase (2 resident blocks at opposite phases).
// ---------------------------------------------------------------------------
__device__ __forceinline__ void dcn_load4(
    bf16x8* c, const ushort_t* __restrict__ xtb, int4 id, int cb)
{
    c[0] = *(const bf16x8*)&xtb[(size_t)id.x * 256 + cb];
    c[1] = *(const bf16x8*)&xtb[(size_t)id.y * 256 + cb];
    c[2] = *(const bf16x8*)&xtb[(size_t)id.z * 256 + cb];
    c[3] = *(const bf16x8*)&xtb[(size_t)id.w * 256 + cb];
}
__device__ __forceinline__ void dcn_proc2(
    ushort_t* swb, int so, const bf16x8* c, float4 wt)
{
    bf16x8 r;
#pragma unroll
    for (int j = 0; j < 8; ++j) {
        const float v = wt.x * bf2f(c[0][j]) + wt.y * bf2f(c[1][j])
                      + wt.z * bf2f(c[2][j]) + wt.w * bf2f(c[3][j]);
        r[j] = (short)f2bf(v);
    }
    *(bf16x8*)&swb[so] = r;
}

__global__ __launch_bounds__(512, 4) void deform_gemm_k(
    const ushort_t* __restrict__ xt_k, const float* __restrict__ koffs,
    const ushort_t* __restrict__ kwgt, float* __restrict__ kout,
    const ushort_t* __restrict__ xt_s, const float* __restrict__ soffs,
    const ushort_t* __restrict__ swgt_, float* __restrict__ sout)
{
    __shared__ __align__(16) ushort_t smp[DM][SSTR];    // 37.9 KB (single buf)
    __shared__ __align__(16) int      sidx[DM][9][4];   // 9.2 KB
    __shared__ __align__(16) float    swt [DM][9][4];   // 9.2 KB

    int H, W, b, px0;
    const ushort_t* xt; const float* offs; const ushort_t* wgt; float* out;
    if (blockIdx.x < 64) {                // kernel: 16 b * 4 tiles
        H = 16; W = 16; xt = xt_k; offs = koffs; wgt = kwgt; out = kout;
        b = blockIdx.x >> 2; px0 = (blockIdx.x & 3) * 64;
    } else {                              // search: 16 b * 16 tiles
        int t2 = blockIdx.x - 64;
        H = 32; W = 32; xt = xt_s; offs = soffs; wgt = swgt_; out = sout;
        b = t2 >> 4; px0 = (t2 & 15) * 64;
    }
    const int HW = H * W;
    const int t = threadIdx.x, lane = t & 63, wv = t >> 6;

    // ---- phase 0: bilinear params, 576 (px,tap) units over 512 threads ----
#pragma unroll
    for (int u = 0; u < 2; ++u) {
        const int s = t + u * 512;
        if (s < DM * 9) {
            const int p = s / 9, k = s - 9 * p;
            const int pix = px0 + p;
            const int h  = pix / W;
            const int wc = pix - h * W;
            const float* ob = offs + (size_t)b * 18 * HW;
            const float dy = ob[(2 * k    ) * HW + pix];
            const float dx = ob[(2 * k + 1) * HW + pix];
            const float sy = (float)(h  + k / 3 - 1) + dy;
            const float sx = (float)(wc + k % 3 - 1) + dx;
            const float y0f = floorf(sy), x0f = floorf(sx);
            const float ly = sy - y0f, lx = sx - x0f;
            const int y0 = (int)y0f, x0 = (int)x0f;
#pragma unroll
            for (int j = 0; j < 4; ++j) {
                const int yy = y0 + (j >> 1);
                const int xx = x0 + (j & 1);
                const bool ok = ((unsigned)yy < (unsigned)H) && ((unsigned)xx < (unsigned)W);
                sidx[p][k][j] = min(max(yy, 0), H - 1) * W + min(max(xx, 0), W - 1);
                const float wj = ((j >> 1) ? ly : 1.f - ly) * ((j & 1) ? lx : 1.f - lx);
                swt[p][k][j] = ok ? wj : 0.f;
            }
        }
    }
    __syncthreads();

    const ushort_t* xtb = xt + (size_t)b * HW * 256;
    const int l15 = lane & 15;
    const int cg8 = (lane >> 4) * 8;
    const int ocb = wv * 32;
    const bool live4 = (t < 256);         // 2304 - 4*512 = 256

    // gather-unit geometry: unit q handles s = t + q*512;
    // g = s>>2 = g0 + q*128 (param index px*9+tap), cg = s&3 = t&3 (const).
    const int g0  = t >> 2;
    const int cgE = (t & 3) * 8;          // element offset within 32-ch chunk
    int uso[5];                           // smp write offsets (elems)
#pragma unroll
    for (int q = 0; q < 5; ++q) {
        const int g  = g0 + q * 128;
        const int px = g / 9, tap = g - 9 * px;
        uso[q] = px * SSTR + tap * 32 + (t & 3) * 8;
    }

    const ushort_t* wrow0 = wgt + (size_t)(ocb      + l15) * K_TOT + cg8;
    const ushort_t* wrow1 = wgt + (size_t)(ocb + 16 + l15) * K_TOT + cg8;
    ushort_t* smpb = &smp[0][0];
    const int4*   sidxF = (const int4*)  &sidx[0][0][0];
    const float4* swtF  = (const float4*)&swt [0][0][0];

    f32x4 acc[4][2] = {};

    for (int cc = 0; cc < NCHK; ++cc) {
        const int cb = cc * 32 + cgE;
        const size_t kg0 = (size_t)cc * KCH;

        // ---- gather phase: 4.5 units/thread, params re-read from LDS ------
#pragma unroll
        for (int q = 0; q < 5; ++q) {
            if (q < 4 || live4) {
                const int  g  = g0 + q * 128;
                const int4   id = sidxF[g];
                const float4 wt = swtF[g];
                bf16x8 c[4];
                dcn_load4(c, xtb, id, cb);
                dcn_proc2(smpb, uso[q], c, wt);
            }
        }

        // B ks0 prefetch: issued pre-barrier, in flight across it
        const bf16x8 pb0 = *(const bf16x8*)&wrow0[kg0];
        const bf16x8 pb1 = *(const bf16x8*)&wrow1[kg0];

        // ---- barrier A: smp writes visible (lgkm only, vmem in flight) ----
        asm volatile("s_waitcnt lgkmcnt(0)" ::: "memory");
        __builtin_amdgcn_sched_barrier(0);
        __builtin_amdgcn_s_barrier();
        __builtin_amdgcn_sched_barrier(0);

        // ---- MFMA phase -----------------------------------------------------
        __builtin_amdgcn_s_setprio(1);
#pragma unroll
        for (int ks = 0; ks < 9; ++ks) {
            const bf16x8 b0 = (ks == 0) ? pb0 : *(const bf16x8*)&wrow0[kg0 + (size_t)ks * 32];
            const bf16x8 b1 = (ks == 0) ? pb1 : *(const bf16x8*)&wrow1[kg0 + (size_t)ks * 32];
            bf16x8 a[4];
#pragma unroll
            for (int mt = 0; mt < 4; ++mt)
                a[mt] = *(const bf16x8*)&smp[mt * 16 + l15][ks * 32 + cg8];
#pragma unroll
            for (int mt = 0; mt < 4; ++mt) {
                acc[mt][0] = __builtin_amdgcn_mfma_f32_16x16x32_bf16(a[mt], b0, acc[mt][0], 0, 0, 0);
                acc[mt][1] = __builtin_amdgcn_mfma_f32_16x16x32_bf16(a[mt], b1, acc[mt][1], 0, 0, 0);
            }
        }
        __builtin_amdgcn_s_setprio(0);

        // ---- barrier B: all smp reads retired before next chunk's writes --
        if (cc < NCHK - 1) {
            __builtin_amdgcn_sched_barrier(0);
            __builtin_amdgcn_s_barrier();
            __builtin_amdgcn_sched_barrier(0);
        }
    }

    // ---- epilogue ---------------------------------------------------------
    const int prow = (lane >> 4) * 4;
#pragma unroll
    for (int mt = 0; mt < 4; ++mt) {
#pragma unroll
        for (int nt = 0; nt < 2; ++nt) {
            const int oc = ocb + nt * 16 + l15;
            float* op = out + ((size_t)b * OC + oc) * HW + px0 + mt * 16 + prow;
            *(float4*)op = *(float4*)&acc[mt][nt];
        }
    }
}

// ---------------------------------------------------------------------------
// Launcher. Inputs: kernel, search, Toffset_w, Toffset_b, Tdeform_w,
//                   Soffset_w, Soffset_b, Sdeform_w
// Outputs: kernel_out[16,256,16,16], search_out[16,256,32,32],
//          kernel_offset[16,18,16,16], search_offset[16,18,32,32]
// d_ws: 13.2 MB (bf16 weights 2.66 MB + HWC inputs 10.5 MB).
// ---------------------------------------------------------------------------
extern "C" void kernel_launch(void* const* d_in, const int* in_sizes, int n_in,
                              void* d_out, int out_size, void* d_ws, size_t ws_size,
                              hipStream_t stream) {
    const float* kin = (const float*)d_in[0];
    const float* sin_ = (const float*)d_in[1];
    const float* tow = (const float*)d_in[2];
    const float* tob = (const float*)d_in[3];
    const float* tdw = (const float*)d_in[4];
    const float* sow = (const float*)d_in[5];
    const float* sob = (const float*)d_in[6];
    const float* sdw = (const float*)d_in[7];

    float* out = (float*)d_out;
    float* out_k  = out;                                      // 16*256*16*16
    float* out_s  = out_k + (size_t)16 * 256 * 16 * 16;       // 16*256*32*32
    float* out_ko = out_s + (size_t)16 * 256 * 32 * 32;       // 16*18*16*16
    float* out_so = out_ko + (size_t)16 * 18 * 16 * 16;       // 16*18*32*32

    ushort_t* wk_d = (ushort_t*)d_ws;                 // [256][2304] tap-major
    ushort_t* ws_d = wk_d + N_DW;
    ushort_t* wk_o = ws_d + N_DW;                     // [32][2304] tap-major
    ushort_t* ws_o = wk_o + N_OW;
    ushort_t* xt_k = ws_o + N_OW;                     // [16][256][256] HWC bf16
    ushort_t* xt_s = xt_k + (size_t)16 * 256 * 256;   // [16][1024][256]

    prep_k<<<dim3(CVT_BLOCKS + 320), 256, 0, stream>>>(
        tdw, sdw, tow, sow, kin, sin_,
        wk_d, ws_d, wk_o, ws_o, xt_k, xt_s);

    conv_gemm_k<<<dim3(320), 256, 0, stream>>>(
        xt_k, wk_o, tob, out_ko, xt_s, ws_o, sob, out_so);

    deform_gemm_k<<<dim3(320), 512, 0, stream>>>(
        xt_k, out_ko, wk_d, out_k, xt_s, out_so, ws_d, out_s);
}